// Round 3
// baseline (341.979 us; speedup 1.0000x reference)
//
#include <hip/hip_runtime.h>
#include <math.h>

// Problem constants (fixed by reference)
#define Cc    256
#define Gg    16
#define KK    9
#define Cgc   16
#define Hh    64
#define Ww    64
#define Ll    4096          // H*W
#define Bb    4
#define HID   1024
#define OMN   432           // G*3*K
#define NTOK  16384         // B*L

typedef unsigned short ushort_t;
typedef __attribute__((ext_vector_type(8))) short bf16x8;   // 8 bf16 (4 VGPRs)
typedef __attribute__((ext_vector_type(4))) float f32x4;    // MFMA accumulator

// ---- fp32 <-> bf16 bit helpers (round-to-nearest-even) ----
__device__ __forceinline__ ushort_t f2bf(float x) {
    unsigned int u = __float_as_uint(x);
    unsigned int r = (u + 0x7fffu + ((u >> 16) & 1u)) >> 16;
    return (ushort_t)r;
}
__device__ __forceinline__ float bf2f(ushort_t h) {
    return __uint_as_float(((unsigned int)h) << 16);
}
__device__ __forceinline__ void split2(float x, ushort_t& h, ushort_t& l) {
    h = f2bf(x);
    l = f2bf(x - bf2f(h));
}

// ---------------------------------------------------------------------------
// Batched transpose: in (B, Rows, Cols) -> out (B, Cols, Rows)
// ---------------------------------------------------------------------------
__global__ void transpose_k(const float* __restrict__ in, float* __restrict__ out,
                            int Rows, int Cols) {
    __shared__ float tile[32][33];
    int b  = blockIdx.z;
    int c0 = blockIdx.x * 32;
    int r0 = blockIdx.y * 32;
    int tx = threadIdx.x;   // 0..31
    int ty = threadIdx.y;   // 0..7
    const float* ip = in + ((size_t)b * Rows + r0) * Cols + c0;
#pragma unroll
    for (int i = 0; i < 32; i += 8)
        tile[ty + i][tx] = ip[(size_t)(ty + i) * Cols + tx];
    __syncthreads();
    float* op = out + ((size_t)b * Cols + c0) * Rows + r0;
#pragma unroll
    for (int i = 0; i < 32; i += 8)
        op[(size_t)(ty + i) * Rows + tx] = tile[tx][ty + i];
}

// ---------------------------------------------------------------------------
// LayerNorm over last dim (C=256). One wave per token; emits bf16 hi/lo.
// ---------------------------------------------------------------------------
__global__ void layernorm_k(const float* __restrict__ in, const float* __restrict__ w,
                            const float* __restrict__ bvec,
                            ushort_t* __restrict__ outh, ushort_t* __restrict__ outl) {
    int row  = blockIdx.x * 4 + (threadIdx.x >> 6);
    int lane = threadIdx.x & 63;
    const float4* ip = (const float4*)(in + (size_t)row * Cc);
    float4 v = ip[lane];
    float s  = v.x + v.y + v.z + v.w;
    float sq = v.x * v.x + v.y * v.y + v.z * v.z + v.w * v.w;
#pragma unroll
    for (int m = 1; m < 64; m <<= 1) {
        s  += __shfl_xor(s, m);
        sq += __shfl_xor(sq, m);
    }
    float mu  = s * (1.0f / Cc);
    float var = sq * (1.0f / Cc) - mu * mu;
    float rs  = rsqrtf(var + 1e-5f);
    float4 wv = ((const float4*)w)[lane];
    float4 bv = ((const float4*)bvec)[lane];
    float o0 = (v.x - mu) * rs * wv.x + bv.x;
    float o1 = (v.y - mu) * rs * wv.y + bv.y;
    float o2 = (v.z - mu) * rs * wv.z + bv.z;
    float o3 = (v.w - mu) * rs * wv.w + bv.w;
    ushort4 hv, lv;
    split2(o0, hv.x, lv.x);
    split2(o1, hv.y, lv.y);
    split2(o2, hv.z, lv.z);
    split2(o3, hv.w, lv.w);
    ((ushort4*)(outh + (size_t)row * Cc))[lane] = hv;
    ((ushort4*)(outl + (size_t)row * Cc))[lane] = lv;
}

// ---------------------------------------------------------------------------
// Weight split: fp32 -> bf16 hi/lo. Grid covers n/1024 blocks.
// ---------------------------------------------------------------------------
__global__ void wsplit_k(const float* __restrict__ in,
                         ushort_t* __restrict__ h, ushort_t* __restrict__ l) {
    int i = blockIdx.x * 256 + threadIdx.x;   // handles 4 elements
    float4 v = ((const float4*)in)[i];
    ushort4 hv, lv;
    split2(v.x, hv.x, lv.x);
    split2(v.y, hv.y, lv.y);
    split2(v.z, hv.z, lv.z);
    split2(v.w, hv.w, lv.w);
    ((ushort4*)h)[i] = hv;
    ((ushort4*)l)[i] = lv;
}

// ---------------------------------------------------------------------------
// Split-bf16 MFMA GEMM: Cout[M,N] = (Ah+Al)[M,K] @ (Wh+Wl)[N,K]^T + bias
//   3-term: Ah*Wh + Ah*Wl + Al*Wh  (error ~2^-16 relative)
// BM=BN=128, BK=32. 512 threads = 8 waves (4 m x 2 n), wave-tile 32x64.
// ACT: 0 none, 1 exact GELU.
// OUT: 0 fp32 row-major [M,N]; 1 bf16 hi/lo pair; 2 fp32 NCHW (B,C,H,W) float4.
// ---------------------------------------------------------------------------
template<bool RES, int ACT, int OUT>
__global__ __launch_bounds__(512)
void gemm_mfma_k(const ushort_t* __restrict__ Ah, const ushort_t* __restrict__ Al,
                 const ushort_t* __restrict__ Wh, const ushort_t* __restrict__ Wl,
                 const float* __restrict__ bias, const float* __restrict__ res,
                 float* __restrict__ Cout, ushort_t* __restrict__ Ch,
                 ushort_t* __restrict__ Cl, int M, int N, int Kd) {
    // LDS tiles: [row][k], k-stride padded 32->40 (80B: 2-way bank alias = free)
    __shared__ ushort_t AsH[128][40];
    __shared__ ushort_t AsL[128][40];
    __shared__ ushort_t BsH[128][40];
    __shared__ ushort_t BsL[128][40];

    int tid  = threadIdx.x;
    int lane = tid & 63;
    int wave = tid >> 6;            // 0..7
    int wm = wave >> 1;             // 0..3 -> m-offset 32*wm
    int wn = wave & 1;              // 0..1 -> n-offset 64*wn
    int m0 = blockIdx.x * 128;
    int n0 = blockIdx.y * 128;

    f32x4 acc[2][4];
#pragma unroll
    for (int i = 0; i < 2; ++i)
#pragma unroll
        for (int j = 0; j < 4; ++j)
#pragma unroll
            for (int r = 0; r < 4; ++r) acc[i][j][r] = 0.0f;

    int lr = tid >> 2;              // 0..127 (staging row)
    int lc = tid & 3;               // 16B chunk within 32-k row

    int fr = lane & 15;             // fragment m/n index
    int ko = (lane >> 4) * 8;       // fragment k offset

    for (int k0 = 0; k0 < Kd; k0 += 32) {
        // ---- stage A rows (one pass: 512 threads cover 128 rows x 4 chunks)
        {
            const ushort_t* p = Ah + (size_t)(m0 + lr) * Kd + k0 + lc * 8;
            const ushort_t* q = Al + (size_t)(m0 + lr) * Kd + k0 + lc * 8;
            *(bf16x8*)&AsH[lr][lc * 8] = *(const bf16x8*)p;
            *(bf16x8*)&AsL[lr][lc * 8] = *(const bf16x8*)q;
        }
        // ---- stage B (Wt row n0+lr; guarded)
        {
            bf16x8 z;
#pragma unroll
            for (int t = 0; t < 8; ++t) z[t] = 0;
            int n1 = n0 + lr;
            bf16x8 bh = z, bl = z;
            if (n1 < N) {
                bh = *(const bf16x8*)(Wh + (size_t)n1 * Kd + k0 + lc * 8);
                bl = *(const bf16x8*)(Wl + (size_t)n1 * Kd + k0 + lc * 8);
            }
            *(bf16x8*)&BsH[lr][lc * 8] = bh;
            *(bf16x8*)&BsL[lr][lc * 8] = bl;
        }
        __syncthreads();

        // ---- fragments + MFMA
        bf16x8 ah[2], al[2], bh[4], bl[4];
#pragma unroll
        for (int i = 0; i < 2; ++i) {
            ah[i] = *(const bf16x8*)&AsH[wm * 32 + i * 16 + fr][ko];
            al[i] = *(const bf16x8*)&AsL[wm * 32 + i * 16 + fr][ko];
        }
#pragma unroll
        for (int j = 0; j < 4; ++j) {
            bh[j] = *(const bf16x8*)&BsH[wn * 64 + j * 16 + fr][ko];
            bl[j] = *(const bf16x8*)&BsL[wn * 64 + j * 16 + fr][ko];
        }
#pragma unroll
        for (int i = 0; i < 2; ++i)
#pragma unroll
            for (int j = 0; j < 4; ++j) {
                acc[i][j] = __builtin_amdgcn_mfma_f32_16x16x32_bf16(ah[i], bh[j], acc[i][j], 0, 0, 0);
                acc[i][j] = __builtin_amdgcn_mfma_f32_16x16x32_bf16(ah[i], bl[j], acc[i][j], 0, 0, 0);
                acc[i][j] = __builtin_amdgcn_mfma_f32_16x16x32_bf16(al[i], bh[j], acc[i][j], 0, 0, 0);
            }
        __syncthreads();
    }

    // ---- epilogue: C/D layout col=lane&15, row=(lane>>4)*4+reg ----
#pragma unroll
    for (int j = 0; j < 4; ++j) {
        int n = n0 + wn * 64 + j * 16 + fr;
        if (n >= N) continue;
        float bv = bias[n];
#pragma unroll
        for (int i = 0; i < 2; ++i) {
            int rb = m0 + wm * 32 + i * 16 + ((lane >> 4) << 2);
            float vr[4];
#pragma unroll
            for (int r = 0; r < 4; ++r) {
                float v = acc[i][j][r] + bv;
                if (ACT == 1) v = 0.5f * v * (1.0f + erff(v * 0.70710678118654752f));
                if (RES) v += res[(size_t)(rb + r) * N + n];
                vr[r] = v;
            }
            if (OUT == 0) {
#pragma unroll
                for (int r = 0; r < 4; ++r)
                    Cout[(size_t)(rb + r) * N + n] = vr[r];
            } else if (OUT == 1) {
#pragma unroll
                for (int r = 0; r < 4; ++r) {
                    ushort_t h, l;
                    split2(vr[r], h, l);
                    Ch[(size_t)(rb + r) * N + n] = h;
                    Cl[(size_t)(rb + r) * N + n] = l;
                }
            } else {
                // NCHW: rows rb..rb+3 are consecutive tokens of one batch ->
                // contiguous float4 at out[b][n][l..l+3]
                int b = rb >> 12;           // token row / L
                int l = rb & 4095;
                float4 o = make_float4(vr[0], vr[1], vr[2], vr[3]);
                *(float4*)&Cout[((size_t)b * Cc + n) * Ll + l] = o;
            }
        }
    }
}

// ---------------------------------------------------------------------------
// DCNv4 bilinear sampling. One block (256 thr) per token; thread = (g, cg).
// v: (B,L,C) fp32; om: (B,L,432); out: bf16 hi/lo (feeds oproj GEMM).
// ---------------------------------------------------------------------------
__global__ __launch_bounds__(256)
void dcn_sample_k(const float* __restrict__ v, const float* __restrict__ om,
                  ushort_t* __restrict__ outh, ushort_t* __restrict__ outl) {
    int token = blockIdx.x;            // 0..B*L-1
    int b = token >> 12;               // L = 4096
    int l = token & 4095;
    int h = l >> 6, w = l & 63;
    int g  = threadIdx.x >> 4;
    int cg = threadIdx.x & 15;

    const float* omp = om + (size_t)token * OMN + g * 27;
    const float* vb  = v + (size_t)b * Ll * Cc + g * Cgc + cg;

    float acc = 0.0f;
#pragma unroll
    for (int k = 0; k < 9; ++k) {
        float dx = (float)(k % 3) - 1.0f;
        float dy = (float)(k / 3) - 1.0f;
        float px = (float)w + dx + omp[2 * k];
        float py = (float)h + dy + omp[2 * k + 1];
        float mk = omp[18 + k];
        float x0f = floorf(px), y0f = floorf(py);
        float tx = px - x0f, ty = py - y0f;
        int x0 = (int)x0f, y0 = (int)y0f;

        float tap[4];
#pragma unroll
        for (int t = 0; t < 4; ++t) {
            int xi = x0 + (t & 1);
            int yi = y0 + (t >> 1);
            bool valid = (xi >= 0) && (xi < Ww) && (yi >= 0) && (yi < Hh);
            int xc = min(max(xi, 0), Ww - 1);
            int yc = min(max(yi, 0), Hh - 1);
            float val = vb[(size_t)(yc * Ww + xc) * Cc];
            tap[t] = valid ? val : 0.0f;
        }
        float s = tap[0] * (1.0f - tx) * (1.0f - ty)
                + tap[1] * tx * (1.0f - ty)
                + tap[2] * (1.0f - tx) * ty
                + tap[3] * tx * ty;
        acc = fmaf(mk, s, acc);
    }
    size_t idx = (size_t)token * Cc + g * Cgc + cg;
    ushort_t hh, ll;
    split2(acc, hh, ll);
    outh[idx] = hh;
    outl[idx] = ll;
}

// ---------------------------------------------------------------------------
extern "C" void kernel_launch(void* const* d_in, const int* in_sizes, int n_in,
                              void* d_out, int out_size, void* d_ws, size_t ws_size,
                              hipStream_t stream) {
    const float* x        = (const float*)d_in[0];
    const float* n1w      = (const float*)d_in[1];
    const float* n1b      = (const float*)d_in[2];
    const float* vproj_w  = (const float*)d_in[3];
    const float* vproj_b  = (const float*)d_in[4];
    const float* om_w     = (const float*)d_in[5];
    const float* om_b     = (const float*)d_in[6];
    const float* oproj_w  = (const float*)d_in[7];
    const float* oproj_b  = (const float*)d_in[8];
    const float* n2w      = (const float*)d_in[9];
    const float* n2b      = (const float*)d_in[10];
    const float* fc1_w    = (const float*)d_in[11];
    const float* fc1_b    = (const float*)d_in[12];
    const float* fc2_w    = (const float*)d_in[13];
    const float* fc2_b    = (const float*)d_in[14];
    float* out = (float*)d_out;

    // ---- workspace layout (~162 MB) ----
    char* base = (char*)d_ws;
    float*    s0   = (float*)base;                          // A: shortcut (B,L,C) fp32, 16MB
    char* pB = base + (size_t)16777216;
    ushort_t* xnh  = (ushort_t*)pB;                         // B: xn hi (reused: sampled hi)
    ushort_t* xnl  = xnh + (size_t)NTOK * Cc;               //    xn lo (reused: sampled lo)
    char* pC = pB + (size_t)16777216;
    float*    vbuf = (float*)pC;                            // C: v fp32, 16MB
    char* pD = pC + (size_t)16777216;
    float*    om   = (float*)pD;                            // D: om fp32 (28.3MB; reused xn2 hi/lo)
    ushort_t* xn2h = (ushort_t*)pD;
    ushort_t* xn2l = xn2h + (size_t)NTOK * Cc;
    char* pE = pD + (size_t)28311552;
    float*    x1   = (float*)pE;                            // E: x1 fp32, 16MB
    char* pF = pE + (size_t)16777216;
    ushort_t* hh   = (ushort_t*)pF;                         // F: h hi/lo, 67MB
    ushort_t* hl   = hh + (size_t)NTOK * HID;
    char* pG = pF + (size_t)67108864;
    ushort_t* wp   = (ushort_t*)pG;                         // G: weight hi/lo (~3 MB)
    ushort_t* vpWh = wp;              ushort_t* vpWl = vpWh + 65536;
    ushort_t* omWh = vpWl + 65536;    ushort_t* omWl = omWh + 110592;
    ushort_t* opWh = omWl + 110592;   ushort_t* opWl = opWh + 65536;
    ushort_t* f1Wh = opWl + 65536;    ushort_t* f1Wl = f1Wh + 262144;
    ushort_t* f2Wh = f1Wl + 262144;   ushort_t* f2Wl = f2Wh + 262144;

    dim3 tblk(32, 8);

    // 0. weight hi/lo splits (tiny)
    wsplit_k<<<64,  256, 0, stream>>>(vproj_w, vpWh, vpWl);
    wsplit_k<<<108, 256, 0, stream>>>(om_w,    omWh, omWl);
    wsplit_k<<<64,  256, 0, stream>>>(oproj_w, opWh, opWl);
    wsplit_k<<<256, 256, 0, stream>>>(fc1_w,   f1Wh, f1Wl);
    wsplit_k<<<256, 256, 0, stream>>>(fc2_w,   f2Wh, f2Wl);

    // 1. NCHW -> NLC (shortcut)
    transpose_k<<<dim3(Ll / 32, Cc / 32, Bb), tblk, 0, stream>>>(x, s0, Cc, Ll);

    // 2. LN1: s0 -> xn hi/lo
    layernorm_k<<<NTOK / 4, 256, 0, stream>>>(s0, n1w, n1b, xnh, xnl);

    // 3. v = xn @ vproj^T + b  (fp32 out)
    gemm_mfma_k<false, 0, 0><<<dim3(NTOK / 128, 2), 512, 0, stream>>>(
        xnh, xnl, vpWh, vpWl, vproj_b, nullptr, vbuf, nullptr, nullptr, NTOK, Cc, Cc);

    // 4. om = xn @ om_w^T + b  (fp32 out, N=432 guarded)
    gemm_mfma_k<false, 0, 0><<<dim3(NTOK / 128, 4), 512, 0, stream>>>(
        xnh, xnl, omWh, omWl, om_b, nullptr, om, nullptr, nullptr, NTOK, OMN, Cc);

    // 5. DCN sampling -> sampled hi/lo (xn region; xn dead)
    dcn_sample_k<<<NTOK, 256, 0, stream>>>(vbuf, om, xnh, xnl);

    // 6. x1 = shortcut + sampled @ oproj^T + b  (fp32 out)
    gemm_mfma_k<true, 0, 0><<<dim3(NTOK / 128, 2), 512, 0, stream>>>(
        xnh, xnl, opWh, opWl, oproj_b, s0, x1, nullptr, nullptr, NTOK, Cc, Cc);

    // 7. LN2: x1 -> xn2 hi/lo (om region; om dead)
    layernorm_k<<<NTOK / 4, 256, 0, stream>>>(x1, n2w, n2b, xn2h, xn2l);

    // 8. h = gelu(xn2 @ fc1^T + b)  (bf16 hi/lo out)
    gemm_mfma_k<false, 1, 1><<<dim3(NTOK / 128, 8), 512, 0, stream>>>(
        xn2h, xn2l, f1Wh, f1Wl, fc1_b, nullptr, nullptr, hh, hl, NTOK, HID, Cc);

    // 9. out = NCHW(x1 + h @ fc2^T + b)  (direct NCHW float4 stores; K=1024)
    gemm_mfma_k<true, 0, 2><<<dim3(NTOK / 128, 2), 512, 0, stream>>>(
        hh, hl, f2Wh, f2Wl, fc2_b, x1, out, nullptr, nullptr, NTOK, Cc, HID);
}

// Round 16
// 316.476 us; speedup vs baseline: 1.0806x; 1.0806x over previous
//
#include <hip/hip_runtime.h>
#include <math.h>

// Problem constants (fixed by reference)
#define Cc    256
#define Gg    16
#define KK    9
#define Cgc   16
#define Hh    64
#define Ww    64
#define Ll    4096          // H*W
#define Bb    4
#define HID   1024
#define OMN   432           // G*3*K
#define NTOK  16384         // B*L

typedef unsigned short ushort_t;
typedef __attribute__((ext_vector_type(8))) short bf16x8;   // 8 bf16 (4 VGPRs)
typedef __attribute__((ext_vector_type(4))) float f32x4;    // MFMA accumulator

// ---- fp32 <-> bf16 bit helpers (round-to-nearest-even) ----
__device__ __forceinline__ ushort_t f2bf(float x) {
    unsigned int u = __float_as_uint(x);
    unsigned int r = (u + 0x7fffu + ((u >> 16) & 1u)) >> 16;
    return (ushort_t)r;
}
__device__ __forceinline__ float bf2f(ushort_t h) {
    return __uint_as_float(((unsigned int)h) << 16);
}
__device__ __forceinline__ void split2(float x, ushort_t& h, ushort_t& l) {
    h = f2bf(x);
    l = f2bf(x - bf2f(h));
}

// ---- async global->LDS, 16B per lane (wave-uniform LDS base + lane*16) ----
__device__ __forceinline__ void gl_lds16(const ushort_t* g, ushort_t* l) {
    __builtin_amdgcn_global_load_lds(
        (__attribute__((address_space(1))) void*)g,
        (__attribute__((address_space(3))) void*)l, 16, 0, 0);
}

// ---------------------------------------------------------------------------
// Batched transpose: in (B, Rows, Cols) -> out (B, Cols, Rows)
// ---------------------------------------------------------------------------
__global__ void transpose_k(const float* __restrict__ in, float* __restrict__ out,
                            int Rows, int Cols) {
    __shared__ float tile[32][33];
    int b  = blockIdx.z;
    int c0 = blockIdx.x * 32;
    int r0 = blockIdx.y * 32;
    int tx = threadIdx.x;   // 0..31
    int ty = threadIdx.y;   // 0..7
    const float* ip = in + ((size_t)b * Rows + r0) * Cols + c0;
#pragma unroll
    for (int i = 0; i < 32; i += 8)
        tile[ty + i][tx] = ip[(size_t)(ty + i) * Cols + tx];
    __syncthreads();
    float* op = out + ((size_t)b * Cols + c0) * Rows + r0;
#pragma unroll
    for (int i = 0; i < 32; i += 8)
        op[(size_t)(ty + i) * Rows + tx] = tile[tx][ty + i];
}

// ---------------------------------------------------------------------------
// LayerNorm over last dim (C=256). One wave per token; emits bf16 hi/lo.
// ---------------------------------------------------------------------------
__global__ void layernorm_k(const float* __restrict__ in, const float* __restrict__ w,
                            const float* __restrict__ bvec,
                            ushort_t* __restrict__ outh, ushort_t* __restrict__ outl) {
    int row  = blockIdx.x * 4 + (threadIdx.x >> 6);
    int lane = threadIdx.x & 63;
    const float4* ip = (const float4*)(in + (size_t)row * Cc);
    float4 v = ip[lane];
    float s  = v.x + v.y + v.z + v.w;
    float sq = v.x * v.x + v.y * v.y + v.z * v.z + v.w * v.w;
#pragma unroll
    for (int m = 1; m < 64; m <<= 1) {
        s  += __shfl_xor(s, m);
        sq += __shfl_xor(sq, m);
    }
    float mu  = s * (1.0f / Cc);
    float var = sq * (1.0f / Cc) - mu * mu;
    float rs  = rsqrtf(var + 1e-5f);
    float4 wv = ((const float4*)w)[lane];
    float4 bv = ((const float4*)bvec)[lane];
    float o0 = (v.x - mu) * rs * wv.x + bv.x;
    float o1 = (v.y - mu) * rs * wv.y + bv.y;
    float o2 = (v.z - mu) * rs * wv.z + bv.z;
    float o3 = (v.w - mu) * rs * wv.w + bv.w;
    ushort4 hv, lv;
    split2(o0, hv.x, lv.x);
    split2(o1, hv.y, lv.y);
    split2(o2, hv.z, lv.z);
    split2(o3, hv.w, lv.w);
    ((ushort4*)(outh + (size_t)row * Cc))[lane] = hv;
    ((ushort4*)(outl + (size_t)row * Cc))[lane] = lv;
}

// ---------------------------------------------------------------------------
// All weight hi/lo splits in ONE dispatch. Block ranges per weight matrix.
// ---------------------------------------------------------------------------
__global__ void wsplit_all_k(const float* __restrict__ w0, const float* __restrict__ w1,
                             const float* __restrict__ w2, const float* __restrict__ w3,
                             const float* __restrict__ w4,
                             ushort_t* __restrict__ d0h, ushort_t* __restrict__ d0l,  // merged vproj+om
                             ushort_t* __restrict__ d2h, ushort_t* __restrict__ d2l,  // oproj
                             ushort_t* __restrict__ d3h, ushort_t* __restrict__ d3l,  // fc1
                             ushort_t* __restrict__ d4h, ushort_t* __restrict__ d4l) {// fc2
    int blk = blockIdx.x;
    const float* src; ushort_t* dh; ushort_t* dl; int off;
    if (blk < 64)       { src = w0; dh = d0h;          dl = d0l;          off = blk; }
    else if (blk < 172) { src = w1; dh = d0h + 65536;  dl = d0l + 65536;  off = blk - 64; }
    else if (blk < 236) { src = w2; dh = d2h;          dl = d2l;          off = blk - 172; }
    else if (blk < 492) { src = w3; dh = d3h;          dl = d3l;          off = blk - 236; }
    else                { src = w4; dh = d4h;          dl = d4l;          off = blk - 492; }
    int i = off * 256 + threadIdx.x;   // float4 index
    float4 v = ((const float4*)src)[i];
    ushort4 hv, lv;
    split2(v.x, hv.x, lv.x);
    split2(v.y, hv.y, lv.y);
    split2(v.z, hv.z, lv.z);
    split2(v.w, hv.w, lv.w);
    ((ushort4*)dh)[i] = hv;
    ((ushort4*)dl)[i] = lv;
}

// ---------------------------------------------------------------------------
// Split-bf16 MFMA GEMM, 2-phase double-buffered global_load_lds pipeline.
//   Cout[M,N] = (Ah+Al)[M,K] @ (Wh+Wl)[N,K]^T + bias  (3-term)
// BM=BN=128, BK=32. 512 threads = 8 waves (4m x 2n), wave-tile 32x64.
// LDS: 2buf x (Ah,Al,Bh,Bl) x [128][32] ushort linear = 64 KB, content
// XOR-swizzled (chunk c at slot c^(row&3)) via pre-swizzled global source.
// ACT: 0 none, 1 exact GELU.
// OUT: 0 fp32 [M,N]; 1 bf16 hi/lo; 2 fp32 NCHW float4; 3 split v/om.
// ---------------------------------------------------------------------------
template<bool RES, int ACT, int OUT>
__global__ __launch_bounds__(512)
void gemm2_k(const ushort_t* __restrict__ Ah, const ushort_t* __restrict__ Al,
             const ushort_t* __restrict__ Wh, const ushort_t* __restrict__ Wl,
             const float* __restrict__ bias, const float* __restrict__ bias2,
             const float* __restrict__ res,
             float* __restrict__ Cout, float* __restrict__ Cout2,
             ushort_t* __restrict__ Ch, ushort_t* __restrict__ Cl,
             int M, int N, int Kd) {
    __shared__ ushort_t sA[2][2][128 * 32];   // [buf][hi/lo][row*32+k]
    __shared__ ushort_t sB[2][2][128 * 32];

    int tid  = threadIdx.x;
    int l    = tid & 63;
    int w    = tid >> 6;            // 0..7
    int wm   = w >> 1;              // 0..3 -> m-offset 32*wm
    int wn   = w & 1;               // 0..1 -> n-offset 64*wn
    int m0   = blockIdx.x * 128;
    int n0   = blockIdx.y * 128;

    // staging geometry: wave w covers tile rows 16w..16w+15; lane l ->
    // row sr, dest slot (l&3); source chunk pre-swizzled c = (l&3)^(sr&3)
    int sr = (w << 4) + (l >> 2);
    int sc = (l & 3) ^ (sr & 3);
    size_t aoff = (size_t)(m0 + sr) * Kd + sc * 8;
    int brow = n0 + sr; if (brow > N - 1) brow = N - 1;   // clamp (guarded cols never stored)
    size_t boff = (size_t)brow * Kd + sc * 8;
    int lbase = w << 9;             // w*512 ushorts = w*1024 B

    // fragment geometry
    int fr  = l & 15;
    int kc  = l >> 4;               // 0..3
    int sl8 = ((kc ^ (fr & 3)) << 3);   // swizzled slot offset in ushorts

    f32x4 acc[2][4];
#pragma unroll
    for (int i = 0; i < 2; ++i)
#pragma unroll
        for (int j = 0; j < 4; ++j)
#pragma unroll
            for (int r = 0; r < 4; ++r) acc[i][j][r] = 0.0f;

    int nt = Kd >> 5;

    // prologue: stage tile 0 into buf 0
    gl_lds16(Ah + aoff, &sA[0][0][lbase]);
    gl_lds16(Al + aoff, &sA[0][1][lbase]);
    gl_lds16(Wh + boff, &sB[0][0][lbase]);
    gl_lds16(Wl + boff, &sB[0][1][lbase]);
    __syncthreads();

    int cur = 0;
    for (int t = 0; t < nt; ++t) {
        // issue next tile's loads early (hide latency under compute)
        if (t + 1 < nt) {
            size_t ko = (size_t)(t + 1) << 5;
            int nb = cur ^ 1;
            gl_lds16(Ah + aoff + ko, &sA[nb][0][lbase]);
            gl_lds16(Al + aoff + ko, &sA[nb][1][lbase]);
            gl_lds16(Wh + boff + ko, &sB[nb][0][lbase]);
            gl_lds16(Wl + boff + ko, &sB[nb][1][lbase]);
        }
        // compute on current buffer
        bf16x8 a_h[2], a_l[2], b_h[4], b_l[4];
#pragma unroll
        for (int i = 0; i < 2; ++i) {
            int R = wm * 32 + i * 16 + fr;
            a_h[i] = *(const bf16x8*)&sA[cur][0][R * 32 + sl8];
            a_l[i] = *(const bf16x8*)&sA[cur][1][R * 32 + sl8];
        }
#pragma unroll
        for (int j = 0; j < 4; ++j) {
            int R = wn * 64 + j * 16 + fr;
            b_h[j] = *(const bf16x8*)&sB[cur][0][R * 32 + sl8];
            b_l[j] = *(const bf16x8*)&sB[cur][1][R * 32 + sl8];
        }
#pragma unroll
        for (int i = 0; i < 2; ++i)
#pragma unroll
            for (int j = 0; j < 4; ++j) {
                acc[i][j] = __builtin_amdgcn_mfma_f32_16x16x32_bf16(a_h[i], b_h[j], acc[i][j], 0, 0, 0);
                acc[i][j] = __builtin_amdgcn_mfma_f32_16x16x32_bf16(a_h[i], b_l[j], acc[i][j], 0, 0, 0);
                acc[i][j] = __builtin_amdgcn_mfma_f32_16x16x32_bf16(a_l[i], b_h[j], acc[i][j], 0, 0, 0);
            }
        __syncthreads();   // drains vmcnt(0)+lgkmcnt(0): next buf staged, cur fully read
        cur ^= 1;
    }

    // ---- epilogue: C/D layout col=lane&15, row=(lane>>4)*4+reg ----
#pragma unroll
    for (int j = 0; j < 4; ++j) {
        int n = n0 + wn * 64 + j * 16 + fr;
        if (n >= N) continue;
        float bv;
        if (OUT == 3) bv = (n < 256) ? bias[n] : bias2[n - 256];
        else          bv = bias[n];
#pragma unroll
        for (int i = 0; i < 2; ++i) {
            int rb = m0 + wm * 32 + i * 16 + ((l >> 4) << 2);
            float vr[4];
#pragma unroll
            for (int r = 0; r < 4; ++r) {
                float v = acc[i][j][r] + bv;
                if (ACT == 1) v = 0.5f * v * (1.0f + erff(v * 0.70710678118654752f));
                if (RES) v += res[(size_t)(rb + r) * N + n];
                vr[r] = v;
            }
            if (OUT == 0) {
#pragma unroll
                for (int r = 0; r < 4; ++r)
                    Cout[(size_t)(rb + r) * N + n] = vr[r];
            } else if (OUT == 1) {
#pragma unroll
                for (int r = 0; r < 4; ++r) {
                    ushort_t h, lo;
                    split2(vr[r], h, lo);
                    Ch[(size_t)(rb + r) * N + n] = h;
                    Cl[(size_t)(rb + r) * N + n] = lo;
                }
            } else if (OUT == 2) {
                // NCHW: rows rb..rb+3 consecutive tokens of one batch
                int b  = rb >> 12;
                int li = rb & 4095;
                float4 o = make_float4(vr[0], vr[1], vr[2], vr[3]);
                *(float4*)&Cout[((size_t)b * Cc + n) * Ll + li] = o;
            } else {  // OUT == 3: split v (n<256) / om (n>=256)
                if (n < 256) {
#pragma unroll
                    for (int r = 0; r < 4; ++r)
                        Cout[(size_t)(rb + r) * 256 + n] = vr[r];
                } else {
#pragma unroll
                    for (int r = 0; r < 4; ++r)
                        Cout2[(size_t)(rb + r) * OMN + (n - 256)] = vr[r];
                }
            }
        }
    }
}

// ---------------------------------------------------------------------------
// DCNv4 bilinear sampling. One block (256 thr) per token; thread = (g, cg).
// om row staged in LDS (kills 16x redundant scalar reads).
// ---------------------------------------------------------------------------
__global__ __launch_bounds__(256)
void dcn_sample_k(const float* __restrict__ v, const float* __restrict__ om,
                  ushort_t* __restrict__ outh, ushort_t* __restrict__ outl) {
    __shared__ float omL[OMN];
    int token = blockIdx.x;            // 0..B*L-1
    int tid = threadIdx.x;
    if (tid < OMN - 256) omL[256 + tid] = om[(size_t)token * OMN + 256 + tid];
    omL[tid] = om[(size_t)token * OMN + tid];
    __syncthreads();

    int b = token >> 12;               // L = 4096
    int lidx = token & 4095;
    int h = lidx >> 6, w = lidx & 63;
    int g  = tid >> 4;
    int cg = tid & 15;

    const float* omp = omL + g * 27;
    const float* vb  = v + (size_t)b * Ll * Cc + g * Cgc + cg;

    float acc = 0.0f;
#pragma unroll
    for (int k = 0; k < 9; ++k) {
        float dx = (float)(k % 3) - 1.0f;
        float dy = (float)(k / 3) - 1.0f;
        float px = (float)w + dx + omp[2 * k];
        float py = (float)h + dy + omp[2 * k + 1];
        float mk = omp[18 + k];
        float x0f = floorf(px), y0f = floorf(py);
        float tx = px - x0f, ty = py - y0f;
        int x0 = (int)x0f, y0 = (int)y0f;

        float tap[4];
#pragma unroll
        for (int t = 0; t < 4; ++t) {
            int xi = x0 + (t & 1);
            int yi = y0 + (t >> 1);
            bool valid = (xi >= 0) && (xi < Ww) && (yi >= 0) && (yi < Hh);
            int xc = min(max(xi, 0), Ww - 1);
            int yc = min(max(yi, 0), Hh - 1);
            float val = vb[(size_t)(yc * Ww + xc) * Cc];
            tap[t] = valid ? val : 0.0f;
        }
        float s = tap[0] * (1.0f - tx) * (1.0f - ty)
                + tap[1] * tx * (1.0f - ty)
                + tap[2] * (1.0f - tx) * ty
                + tap[3] * tx * ty;
        acc = fmaf(mk, s, acc);
    }
    size_t idx = (size_t)token * Cc + g * Cgc + cg;
    ushort_t hh, ll;
    split2(acc, hh, ll);
    outh[idx] = hh;
    outl[idx] = ll;
}

// ---------------------------------------------------------------------------
extern "C" void kernel_launch(void* const* d_in, const int* in_sizes, int n_in,
                              void* d_out, int out_size, void* d_ws, size_t ws_size,
                              hipStream_t stream) {
    const float* x        = (const float*)d_in[0];
    const float* n1w      = (const float*)d_in[1];
    const float* n1b      = (const float*)d_in[2];
    const float* vproj_w  = (const float*)d_in[3];
    const float* vproj_b  = (const float*)d_in[4];
    const float* om_w     = (const float*)d_in[5];
    const float* om_b     = (const float*)d_in[6];
    const float* oproj_w  = (const float*)d_in[7];
    const float* oproj_b  = (const float*)d_in[8];
    const float* n2w      = (const float*)d_in[9];
    const float* n2b      = (const float*)d_in[10];
    const float* fc1_w    = (const float*)d_in[11];
    const float* fc1_b    = (const float*)d_in[12];
    const float* fc2_w    = (const float*)d_in[13];
    const float* fc2_b    = (const float*)d_in[14];
    float* out = (float*)d_out;

    // ---- workspace layout (~163 MB) ----
    char* base = (char*)d_ws;
    float*    s0   = (float*)base;                          // shortcut (B,L,C) fp32, 16MB
    char* pB = base + (size_t)16777216;
    ushort_t* xnh  = (ushort_t*)pB;                         // xn hi (reused: sampled hi)
    ushort_t* xnl  = xnh + (size_t)NTOK * Cc;               // xn lo (reused: sampled lo)
    char* pC = pB + (size_t)16777216;
    float*    vbuf = (float*)pC;                            // v fp32 [NTOK][256], 16MB
    char* pD = pC + (size_t)16777216;
    float*    om   = (float*)pD;                            // om fp32 [NTOK][432] (reused xn2 hi/lo)
    ushort_t* xn2h = (ushort_t*)pD;
    ushort_t* xn2l = xn2h + (size_t)NTOK * Cc;
    char* pE = pD + (size_t)28311552;
    float*    x1   = (float*)pE;                            // x1 fp32, 16MB
    char* pF = pE + (size_t)16777216;
    ushort_t* hh   = (ushort_t*)pF;                         // h hi/lo, 67MB
    ushort_t* hl   = hh + (size_t)NTOK * HID;
    char* pG = pF + (size_t)67108864;
    ushort_t* wp   = (ushort_t*)pG;                         // weights hi/lo (~3 MB)
    ushort_t* mWh  = wp;                                    // merged vproj+om [688][256]
    ushort_t* mWl  = mWh + 176128;
    ushort_t* opWh = mWl + 176128;    ushort_t* opWl = opWh + 65536;
    ushort_t* f1Wh = opWl + 65536;    ushort_t* f1Wl = f1Wh + 262144;
    ushort_t* f2Wh = f1Wl + 262144;   ushort_t* f2Wl = f2Wh + 262144;

    dim3 tblk(32, 8);

    // 0. all weight hi/lo splits (one dispatch)
    wsplit_all_k<<<748, 256, 0, stream>>>(vproj_w, om_w, oproj_w, fc1_w, fc2_w,
                                          mWh, mWl, opWh, opWl, f1Wh, f1Wl, f2Wh, f2Wl);

    // 1. NCHW -> NLC (shortcut)
    transpose_k<<<dim3(Ll / 32, Cc / 32, Bb), tblk, 0, stream>>>(x, s0, Cc, Ll);

    // 2. LN1: s0 -> xn hi/lo
    layernorm_k<<<NTOK / 4, 256, 0, stream>>>(s0, n1w, n1b, xnh, xnl);

    // 3+4. merged [v | om] = xn @ [vproj_w; om_w]^T + [b; b]  (N=688, split store)
    gemm2_k<false, 0, 3><<<dim3(NTOK / 128, 6), 512, 0, stream>>>(
        xnh, xnl, mWh, mWl, vproj_b, om_b, nullptr,
        vbuf, om, nullptr, nullptr, NTOK, 688, Cc);

    // 5. DCN sampling -> sampled hi/lo (xn region; xn dead)
    dcn_sample_k<<<NTOK, 256, 0, stream>>>(vbuf, om, xnh, xnl);

    // 6. x1 = shortcut + sampled @ oproj^T + b
    gemm2_k<true, 0, 0><<<dim3(NTOK / 128, 2), 512, 0, stream>>>(
        xnh, xnl, opWh, opWl, oproj_b, nullptr, s0,
        x1, nullptr, nullptr, nullptr, NTOK, Cc, Cc);

    // 7. LN2: x1 -> xn2 hi/lo (om region; om dead)
    layernorm_k<<<NTOK / 4, 256, 0, stream>>>(x1, n2w, n2b, xn2h, xn2l);

    // 8. h = gelu(xn2 @ fc1^T + b)  (bf16 hi/lo out)
    gemm2_k<false, 1, 1><<<dim3(NTOK / 128, 8), 512, 0, stream>>>(
        xn2h, xn2l, f1Wh, f1Wl, fc1_b, nullptr, nullptr,
        nullptr, nullptr, hh, hl, NTOK, HID, Cc);

    // 9. out = NCHW(x1 + h @ fc2^T + b)  (direct NCHW float4 stores; K=1024)
    gemm2_k<true, 0, 2><<<dim3(NTOK / 128, 2), 512, 0, stream>>>(
        hh, hl, f2Wh, f2Wl, fc2_b, nullptr, x1,
        out, nullptr, nullptr, nullptr, NTOK, Cc, HID);
}